// Round 1
// baseline (364.339 us; speedup 1.0000x reference)
//
#include <hip/hip_runtime.h>

#define NNODES 8192
#define NFEAT  128
#define NHID   32
#define NMETA  3
#define NCLASS 16
#define ALPHA  0.2f

typedef __attribute__((ext_vector_type(4))) float  f32x4;
typedef __attribute__((ext_vector_type(8))) __bf16 bf16x8;

// ---------------------------------------------------------------------------
// Kernel 1: T1t[m][h][v] = sum_f x[v][f] * W1[m][f][h]   (bf16 output, transposed)
// ---------------------------------------------------------------------------
__global__ __launch_bounds__(256)
void k_xw(const float* __restrict__ x,      // [N][128]
          const float* __restrict__ W1,     // [NMETA][128][32]
          __bf16* __restrict__ T1t)         // [NMETA][32][N]
{
    __shared__ float w[NFEAT * NHID];       // 16 KB
    const int m = blockIdx.y;
    const int t = threadIdx.x;
    for (int idx = t; idx < NFEAT * NHID; idx += 256)
        w[idx] = W1[m * NFEAT * NHID + idx];
    __syncthreads();

    const int v = blockIdx.x * 256 + t;
    float acc[NHID];
#pragma unroll
    for (int h = 0; h < NHID; ++h) acc[h] = 0.f;

    const f32x4* xr = (const f32x4*)(x + (size_t)v * NFEAT);
    for (int f4 = 0; f4 < NFEAT / 4; ++f4) {
        f32x4 xv = xr[f4];
#pragma unroll
        for (int ff = 0; ff < 4; ++ff) {
            float xs = xv[ff];
#pragma unroll
            for (int h = 0; h < NHID; ++h)
                acc[h] += xs * w[(f4 * 4 + ff) * NHID + h];
        }
    }
#pragma unroll
    for (int h = 0; h < NHID; ++h)
        T1t[((size_t)m * NHID + h) * NNODES + v] = (__bf16)acc[h];
}

// ---------------------------------------------------------------------------
// Kernel 2/4: spmm:  out[m][u][c] = relu( sum_v A[m][u][v] * Bt[m][c][v] + bias[m][c] )
// One wave per block; wave computes 32 rows x 32 cols via 2x2 mfma_16x16x32 frags.
// A (f32) converted to bf16 in registers; B pre-transposed bf16 (L2-resident).
// No LDS, no barriers — pure streaming.
// ---------------------------------------------------------------------------
template<int OUT_BF16>
__global__ __launch_bounds__(64)
void k_spmm(const float*  __restrict__ adj,   // [NMETA][N][N]
            const __bf16* __restrict__ Bt,    // [NMETA][32][N]
            const float*  __restrict__ bias,  // [NMETA][32]
            void* __restrict__ outp)          // [NMETA][N][32] (bf16 or f32)
{
    const int lane = threadIdx.x;     // 0..63
    const int ln15 = lane & 15;
    const int kg   = lane >> 4;       // 0..3
    const int m    = blockIdx.y;
    const int u0   = blockIdx.x * 32;

    const float*  A0 = adj + (size_t)m * NNODES * NNODES
                           + (size_t)(u0 + ln15) * NNODES + kg * 8;
    const float*  A1 = A0 + (size_t)16 * NNODES;
    const __bf16* B0 = Bt + (size_t)m * NHID * NNODES
                           + (size_t)ln15 * NNODES + kg * 8;
    const __bf16* B1 = B0 + (size_t)16 * NNODES;

    f32x4 acc00 = {0.f,0.f,0.f,0.f};
    f32x4 acc01 = {0.f,0.f,0.f,0.f};
    f32x4 acc10 = {0.f,0.f,0.f,0.f};
    f32x4 acc11 = {0.f,0.f,0.f,0.f};

    for (int k0 = 0; k0 < NNODES; k0 += 32 * 4) {
#pragma unroll
        for (int kk = 0; kk < 4; ++kk) {
            const int k = k0 + kk * 32;
            f32x4 a0l = *(const f32x4*)(A0 + k);
            f32x4 a0h = *(const f32x4*)(A0 + k + 4);
            f32x4 a1l = *(const f32x4*)(A1 + k);
            f32x4 a1h = *(const f32x4*)(A1 + k + 4);
            bf16x8 b0 = *(const bf16x8*)(B0 + k);
            bf16x8 b1 = *(const bf16x8*)(B1 + k);
            bf16x8 a0, a1;
#pragma unroll
            for (int e = 0; e < 4; ++e) {
                a0[e]     = (__bf16)a0l[e];
                a0[e + 4] = (__bf16)a0h[e];
                a1[e]     = (__bf16)a1l[e];
                a1[e + 4] = (__bf16)a1h[e];
            }
            acc00 = __builtin_amdgcn_mfma_f32_16x16x32_bf16(a0, b0, acc00, 0, 0, 0);
            acc01 = __builtin_amdgcn_mfma_f32_16x16x32_bf16(a0, b1, acc01, 0, 0, 0);
            acc10 = __builtin_amdgcn_mfma_f32_16x16x32_bf16(a1, b0, acc10, 0, 0, 0);
            acc11 = __builtin_amdgcn_mfma_f32_16x16x32_bf16(a1, b1, acc11, 0, 0, 0);
        }
    }

    // C/D layout (verified m89): col = lane&15, row = (lane>>4)*4 + reg
    const float* bm = bias + m * NHID;
#pragma unroll
    for (int i = 0; i < 2; ++i) {
#pragma unroll
        for (int j = 0; j < 2; ++j) {
            f32x4 acc = (i == 0) ? (j == 0 ? acc00 : acc01)
                                 : (j == 0 ? acc10 : acc11);
            const int   c = 16 * j + ln15;
            const float b = bm[c];
#pragma unroll
            for (int e = 0; e < 4; ++e) {
                const int u = u0 + 16 * i + 4 * kg + e;
                float val = acc[e] + b;
                val = val > 0.f ? val : 0.f;
                const size_t idx = ((size_t)m * NNODES + u) * NHID + c;
                if (OUT_BF16) ((__bf16*)outp)[idx] = (__bf16)val;
                else          ((float*)outp)[idx]  = val;
            }
        }
    }
}

// ---------------------------------------------------------------------------
// Kernel 3: T2t[m][d][v] = sum_h h1[m][v][h] * W2[m][h][d]   (bf16, transposed)
// ---------------------------------------------------------------------------
__global__ __launch_bounds__(256)
void k_hw(const __bf16* __restrict__ h1,   // [NMETA][N][32] bf16
          const float*  __restrict__ W2,   // [NMETA][32][32]
          __bf16* __restrict__ T2t)        // [NMETA][32][N]
{
    __shared__ float w[NHID * NHID];       // 4 KB
    const int m = blockIdx.y;
    const int t = threadIdx.x;
    for (int idx = t; idx < NHID * NHID; idx += 256)
        w[idx] = W2[m * NHID * NHID + idx];
    __syncthreads();

    const int v = blockIdx.x * 256 + t;
    const __bf16* hr = h1 + ((size_t)m * NNODES + v) * NHID;
    float hv[NHID];
#pragma unroll
    for (int i = 0; i < 4; ++i) {
        bf16x8 hb = *(const bf16x8*)(hr + i * 8);
#pragma unroll
        for (int e = 0; e < 8; ++e) hv[i * 8 + e] = (float)hb[e];
    }

    float acc[NHID];
#pragma unroll
    for (int d = 0; d < NHID; ++d) acc[d] = 0.f;
    for (int h = 0; h < NHID; ++h) {
        const float hs = hv[h];
#pragma unroll
        for (int d = 0; d < NHID; ++d)
            acc[d] += hs * w[h * NHID + d];
    }
#pragma unroll
    for (int d = 0; d < NHID; ++d)
        T2t[((size_t)m * NHID + d) * NNODES + v] = (__bf16)acc[d];
}

// ---------------------------------------------------------------------------
// Kernel 5: metapath attention + linear + log_softmax (one thread per node)
// ---------------------------------------------------------------------------
__global__ __launch_bounds__(256)
void k_final(const float* __restrict__ h2,   // [NMETA][N][32] f32
             const float* __restrict__ a,    // [32]
             const float* __restrict__ Wl,   // [32][16]
             const float* __restrict__ bl,   // [16]
             float* __restrict__ out)        // [N][16]
{
    __shared__ float ws_a[NHID];
    __shared__ float ws_w[NHID * NCLASS];
    __shared__ float ws_b[NCLASS];
    const int t = threadIdx.x;
    if (t < NHID) ws_a[t] = a[t];
    for (int idx = t; idx < NHID * NCLASS; idx += 256) ws_w[idx] = Wl[idx];
    if (t < NCLASS) ws_b[t] = bl[t];
    __syncthreads();

    const int n = blockIdx.x * 256 + t;

    float hv[NMETA][NHID];
#pragma unroll
    for (int m = 0; m < NMETA; ++m) {
        const f32x4* hp = (const f32x4*)(h2 + ((size_t)m * NNODES + n) * NHID);
#pragma unroll
        for (int d4 = 0; d4 < NHID / 4; ++d4) {
            f32x4 v = hp[d4];
#pragma unroll
            for (int e = 0; e < 4; ++e) hv[m][d4 * 4 + e] = v[e];
        }
    }

    // e[m] = leaky_relu(h2[m] . a)
    float em[NMETA];
#pragma unroll
    for (int m = 0; m < NMETA; ++m) {
        float d = 0.f;
#pragma unroll
        for (int h = 0; h < NHID; ++h) d += hv[m][h] * ws_a[h];
        em[m] = d > 0.f ? d : ALPHA * d;
    }

    // softmax over metapaths
    float mx = fmaxf(em[0], fmaxf(em[1], em[2]));
    float w0 = __expf(em[0] - mx);
    float w1 = __expf(em[1] - mx);
    float w2 = __expf(em[2] - mx);
    float inv = 1.f / (w0 + w1 + w2);
    w0 *= inv; w1 *= inv; w2 *= inv;

    float o[NHID];
#pragma unroll
    for (int d = 0; d < NHID; ++d)
        o[d] = w0 * hv[0][d] + w1 * hv[1][d] + w2 * hv[2][d];

    // logits = relu(o @ Wl + bl)
    float lg[NCLASS];
#pragma unroll
    for (int c = 0; c < NCLASS; ++c) lg[c] = ws_b[c];
    for (int d = 0; d < NHID; ++d) {
        const float od = o[d];
#pragma unroll
        for (int c = 0; c < NCLASS; ++c) lg[c] += od * ws_w[d * NCLASS + c];
    }
#pragma unroll
    for (int c = 0; c < NCLASS; ++c) lg[c] = lg[c] > 0.f ? lg[c] : 0.f;

    // log_softmax
    float lmx = lg[0];
#pragma unroll
    for (int c = 1; c < NCLASS; ++c) lmx = fmaxf(lmx, lg[c]);
    float ls = 0.f;
#pragma unroll
    for (int c = 0; c < NCLASS; ++c) ls += __expf(lg[c] - lmx);
    const float lse = lmx + __logf(ls);
#pragma unroll
    for (int c = 0; c < NCLASS; ++c)
        out[(size_t)n * NCLASS + c] = lg[c] - lse;
}

// ---------------------------------------------------------------------------
extern "C" void kernel_launch(void* const* d_in, const int* in_sizes, int n_in,
                              void* d_out, int out_size, void* d_ws, size_t ws_size,
                              hipStream_t stream) {
    const float* x    = (const float*)d_in[0];
    const float* adjs = (const float*)d_in[1];
    const float* W1   = (const float*)d_in[2];
    const float* b1   = (const float*)d_in[3];
    const float* W2   = (const float*)d_in[4];
    const float* b2   = (const float*)d_in[5];
    const float* a    = (const float*)d_in[6];
    const float* Wl   = (const float*)d_in[7];
    const float* bl   = (const float*)d_in[8];
    float* out = (float*)d_out;

    char* ws = (char*)d_ws;
    // layout (2 MB strides): T1t 1.5MB | h1 1.5MB | T2t 1.5MB | h2 3MB
    __bf16* T1t = (__bf16*)(ws);
    __bf16* h1  = (__bf16*)(ws + (2u << 20));
    __bf16* T2t = (__bf16*)(ws + (4u << 20));
    float*  h2  = (float*) (ws + (6u << 20));

    dim3 gsmall(NNODES / 256, NMETA);
    dim3 gspmm(NNODES / 32, NMETA);

    k_xw<<<gsmall, 256, 0, stream>>>(x, W1, T1t);
    k_spmm<1><<<gspmm, 64, 0, stream>>>(adjs, T1t, b1, (void*)h1);
    k_hw<<<gsmall, 256, 0, stream>>>(h1, W2, T2t);
    k_spmm<0><<<gspmm, 64, 0, stream>>>(adjs, T2t, b2, (void*)h2);
    k_final<<<NNODES / 256, 256, 0, stream>>>(h2, a, Wl, bl, out);
}

// Round 2
// 350.497 us; speedup vs baseline: 1.0395x; 1.0395x over previous
//
#include <hip/hip_runtime.h>

#define NNODES 8192
#define NFEAT  128
#define NHID   32
#define NMETA  3
#define NCLASS 16
#define ALPHA  0.2f
#define KSPLIT 4
#define KRANGE (NNODES / KSPLIT)   // 2048

typedef __attribute__((ext_vector_type(4))) float        f32x4;
typedef __attribute__((ext_vector_type(8))) __bf16       bf16x8;
typedef __attribute__((ext_vector_type(2))) unsigned int u32x2;

// A8 fragment layout: A8[m][u/16][k/32][lane][8B], lane mapping row=lane&15,
// k = (lane>>4)*8 + byte  (same per-lane mapping as the verified bf16 frags).
#define A8_FRAGS_PER_M   (NNODES / 16)            // 512
#define A8_KBLKS         (NNODES / 32)            // 256
__device__ __forceinline__ size_t a8_off(int m, int frag, int kb, int lane) {
    return ((((size_t)m * A8_FRAGS_PER_M + frag) * A8_KBLKS + kb) * 64 + lane) * 8;
}

// ---------------------------------------------------------------------------
// Kernel 1: T1t[m][h][v] = x[v][:] @ W1[m][:][h]   (bf16, transposed)
// ---------------------------------------------------------------------------
__global__ __launch_bounds__(256)
void k_xw(const float* __restrict__ x, const float* __restrict__ W1,
          __bf16* __restrict__ T1t)
{
    __shared__ float w[NFEAT * NHID];
    const int m = blockIdx.y, t = threadIdx.x;
    for (int idx = t; idx < NFEAT * NHID; idx += 256)
        w[idx] = W1[m * NFEAT * NHID + idx];
    __syncthreads();

    const int v = blockIdx.x * 256 + t;
    float acc[NHID];
#pragma unroll
    for (int h = 0; h < NHID; ++h) acc[h] = 0.f;
    const f32x4* xr = (const f32x4*)(x + (size_t)v * NFEAT);
    for (int f4 = 0; f4 < NFEAT / 4; ++f4) {
        f32x4 xv = xr[f4];
#pragma unroll
        for (int ff = 0; ff < 4; ++ff) {
            float xs = xv[ff];
#pragma unroll
            for (int h = 0; h < NHID; ++h)
                acc[h] += xs * w[(f4 * 4 + ff) * NHID + h];
        }
    }
#pragma unroll
    for (int h = 0; h < NHID; ++h)
        T1t[((size_t)m * NHID + h) * NNODES + v] = (__bf16)acc[h];
}

// ---------------------------------------------------------------------------
// Kernel 2: spmm pass 1 (bf16 MFMA).  grid (256 rowblk, KSPLIT, NMETA), 64 thr.
//  - reads f32 adj rows (32 rows x 2048 K per wave)
//  - bf16 MFMA vs T1t            -> h1p4[kz][m][u][c] f32 partials
//  - side-writes fp8(adj*8192) fragments for pass 2
// ---------------------------------------------------------------------------
__global__ __launch_bounds__(64)
void k_spmm1(const float* __restrict__ adj, const __bf16* __restrict__ Bt,
             unsigned char* __restrict__ A8, float* __restrict__ h1p4)
{
    const int lane = threadIdx.x;
    const int ln15 = lane & 15;
    const int kg   = lane >> 4;
    const int bx   = blockIdx.x;          // row block (32 rows)
    const int kz   = blockIdx.y;          // K split
    const int m    = blockIdx.z;
    const int u0   = bx * 32;
    const int kbeg = kz * KRANGE;

    const float*  A0 = adj + (size_t)m * NNODES * NNODES
                           + (size_t)(u0 + ln15) * NNODES + kg * 8;
    const float*  A1 = A0 + (size_t)16 * NNODES;
    const __bf16* B0 = Bt + (size_t)m * NHID * NNODES
                           + (size_t)ln15 * NNODES + kg * 8;
    const __bf16* B1 = B0 + (size_t)16 * NNODES;

    u32x2* A8f0 = (u32x2*)(A8 + a8_off(m, bx * 2 + 0, 0, lane));
    u32x2* A8f1 = (u32x2*)(A8 + a8_off(m, bx * 2 + 1, 0, lane));

    f32x4 acc00 = {0.f,0.f,0.f,0.f}, acc01 = {0.f,0.f,0.f,0.f};
    f32x4 acc10 = {0.f,0.f,0.f,0.f}, acc11 = {0.f,0.f,0.f,0.f};
    const float S = 8192.0f;

    for (int k0 = kbeg; k0 < kbeg + KRANGE; k0 += 128) {
#pragma unroll
        for (int kk = 0; kk < 4; ++kk) {
            const int k  = k0 + kk * 32;
            const int kb = k >> 5;                  // global k-block
            f32x4 a0l = *(const f32x4*)(A0 + k);
            f32x4 a0h = *(const f32x4*)(A0 + k + 4);
            f32x4 a1l = *(const f32x4*)(A1 + k);
            f32x4 a1h = *(const f32x4*)(A1 + k + 4);
            bf16x8 b0 = *(const bf16x8*)(B0 + k);
            bf16x8 b1 = *(const bf16x8*)(B1 + k);
            bf16x8 a0, a1;
#pragma unroll
            for (int e = 0; e < 4; ++e) {
                a0[e] = (__bf16)a0l[e];  a0[e + 4] = (__bf16)a0h[e];
                a1[e] = (__bf16)a1l[e];  a1[e + 4] = (__bf16)a1h[e];
            }
            acc00 = __builtin_amdgcn_mfma_f32_16x16x32_bf16(a0, b0, acc00, 0, 0, 0);
            acc01 = __builtin_amdgcn_mfma_f32_16x16x32_bf16(a0, b1, acc01, 0, 0, 0);
            acc10 = __builtin_amdgcn_mfma_f32_16x16x32_bf16(a1, b0, acc10, 0, 0, 0);
            acc11 = __builtin_amdgcn_mfma_f32_16x16x32_bf16(a1, b1, acc11, 0, 0, 0);

            // fp8(adj*8192) fragment side-write
            unsigned int p;
            u32x2 q;
            p = __builtin_amdgcn_cvt_pk_fp8_f32(a0l[0]*S, a0l[1]*S, 0u, false);
            p = __builtin_amdgcn_cvt_pk_fp8_f32(a0l[2]*S, a0l[3]*S, p,  true);
            q.x = p;
            p = __builtin_amdgcn_cvt_pk_fp8_f32(a0h[0]*S, a0h[1]*S, 0u, false);
            p = __builtin_amdgcn_cvt_pk_fp8_f32(a0h[2]*S, a0h[3]*S, p,  true);
            q.y = p;
            A8f0[(size_t)kb * 64] = q;
            p = __builtin_amdgcn_cvt_pk_fp8_f32(a1l[0]*S, a1l[1]*S, 0u, false);
            p = __builtin_amdgcn_cvt_pk_fp8_f32(a1l[2]*S, a1l[3]*S, p,  true);
            q.x = p;
            p = __builtin_amdgcn_cvt_pk_fp8_f32(a1h[0]*S, a1h[1]*S, 0u, false);
            p = __builtin_amdgcn_cvt_pk_fp8_f32(a1h[2]*S, a1h[3]*S, p,  true);
            q.y = p;
            A8f1[(size_t)kb * 64] = q;
        }
    }

    // partials: h1p4[(kz*NMETA+m)][u][c]
    float* hp = h1p4 + (((size_t)kz * NMETA + m) * NNODES) * NHID;
#pragma unroll
    for (int i = 0; i < 2; ++i) {
#pragma unroll
        for (int j = 0; j < 2; ++j) {
            f32x4 acc = (i == 0) ? (j == 0 ? acc00 : acc01)
                                 : (j == 0 ? acc10 : acc11);
            const int c = 16 * j + ln15;
#pragma unroll
            for (int e = 0; e < 4; ++e) {
                const int u = u0 + 16 * i + 4 * kg + e;
                hp[(size_t)u * NHID + c] = acc[e];
            }
        }
    }
}

// ---------------------------------------------------------------------------
// Kernel 3: h1 = relu(sum_kz h1p4 + b1); T2t8[m][d][v] = fp8(64 * h1 @ W2)
// ---------------------------------------------------------------------------
__global__ __launch_bounds__(256)
void k_hw(const float* __restrict__ h1p4, const float* __restrict__ b1,
          const float* __restrict__ W2, unsigned char* __restrict__ T2t8)
{
    __shared__ float w[NHID * NHID];
    __shared__ float bs[NHID];
    const int m = blockIdx.y, t = threadIdx.x;
    for (int idx = t; idx < NHID * NHID; idx += 256)
        w[idx] = W2[m * NHID * NHID + idx];
    if (t < NHID) bs[t] = b1[m * NHID + t];
    __syncthreads();

    const int v = blockIdx.x * 256 + t;
    float h[NHID];
#pragma unroll
    for (int d4 = 0; d4 < NHID / 4; ++d4) {
        f32x4 s = {0.f,0.f,0.f,0.f};
#pragma unroll
        for (int kz = 0; kz < KSPLIT; ++kz) {
            const f32x4* hp = (const f32x4*)(h1p4 +
                (((size_t)kz * NMETA + m) * NNODES + v) * NHID);
            s += hp[d4];
        }
#pragma unroll
        for (int e = 0; e < 4; ++e) {
            float val = s[e] + bs[d4 * 4 + e];
            h[d4 * 4 + e] = val > 0.f ? val : 0.f;
        }
    }

    float acc[NHID];
#pragma unroll
    for (int d = 0; d < NHID; ++d) acc[d] = 0.f;
    for (int hh = 0; hh < NHID; ++hh) {
        const float hs = h[hh];
#pragma unroll
        for (int d = 0; d < NHID; ++d) acc[d] += hs * w[hh * NHID + d];
    }
#pragma unroll
    for (int d = 0; d < NHID; ++d) {
        unsigned int p = __builtin_amdgcn_cvt_pk_fp8_f32(acc[d] * 64.0f, 0.f, 0u, false);
        T2t8[((size_t)m * NHID + d) * NNODES + v] = (unsigned char)(p & 0xff);
    }
}

// ---------------------------------------------------------------------------
// Kernel 4: spmm pass 2 (fp8 MFMA on A8 frags + T2t8) -> h2p4 partials
// ---------------------------------------------------------------------------
__global__ __launch_bounds__(64)
void k_spmm2(const unsigned char* __restrict__ A8,
             const unsigned char* __restrict__ T2t8,
             float* __restrict__ h2p4)
{
    const int lane = threadIdx.x;
    const int ln15 = lane & 15;
    const int kg   = lane >> 4;
    const int bx   = blockIdx.x;
    const int kz   = blockIdx.y;
    const int m    = blockIdx.z;
    const int u0   = bx * 32;
    const int kbeg = kz * KRANGE;

    const long* A8f0 = (const long*)(A8 + a8_off(m, bx * 2 + 0, 0, lane));
    const long* A8f1 = (const long*)(A8 + a8_off(m, bx * 2 + 1, 0, lane));
    const unsigned char* B0 = T2t8 + (size_t)m * NHID * NNODES
                                   + (size_t)ln15 * NNODES + kg * 8;
    const unsigned char* B1 = B0 + (size_t)16 * NNODES;

    f32x4 acc00 = {0.f,0.f,0.f,0.f}, acc01 = {0.f,0.f,0.f,0.f};
    f32x4 acc10 = {0.f,0.f,0.f,0.f}, acc11 = {0.f,0.f,0.f,0.f};

    for (int k0 = kbeg; k0 < kbeg + KRANGE; k0 += 256) {
#pragma unroll
        for (int kk = 0; kk < 8; ++kk) {
            const int k  = k0 + kk * 32;
            const int kb = k >> 5;
            long a0 = A8f0[(size_t)kb * 64];
            long a1 = A8f1[(size_t)kb * 64];
            long b0 = *(const long*)(B0 + k);
            long b1 = *(const long*)(B1 + k);
            acc00 = __builtin_amdgcn_mfma_f32_16x16x32_fp8_fp8(a0, b0, acc00, 0, 0, 0);
            acc01 = __builtin_amdgcn_mfma_f32_16x16x32_fp8_fp8(a0, b1, acc01, 0, 0, 0);
            acc10 = __builtin_amdgcn_mfma_f32_16x16x32_fp8_fp8(a1, b0, acc10, 0, 0, 0);
            acc11 = __builtin_amdgcn_mfma_f32_16x16x32_fp8_fp8(a1, b1, acc11, 0, 0, 0);
        }
    }

    const float INV = 1.0f / (8192.0f * 64.0f);   // undo A and B scales
    float* hp = h2p4 + (((size_t)kz * NMETA + m) * NNODES) * NHID;
#pragma unroll
    for (int i = 0; i < 2; ++i) {
#pragma unroll
        for (int j = 0; j < 2; ++j) {
            f32x4 acc = (i == 0) ? (j == 0 ? acc00 : acc01)
                                 : (j == 0 ? acc10 : acc11);
            const int c = 16 * j + ln15;
#pragma unroll
            for (int e = 0; e < 4; ++e) {
                const int u = u0 + 16 * i + 4 * kg + e;
                hp[(size_t)u * NHID + c] = acc[e] * INV;
            }
        }
    }
}

// ---------------------------------------------------------------------------
// Kernel 5: h2 = relu(sum_kz h2p4 + b2); attention + linear + log_softmax
// ---------------------------------------------------------------------------
__global__ __launch_bounds__(256)
void k_final(const float* __restrict__ h2p4, const float* __restrict__ b2,
             const float* __restrict__ a, const float* __restrict__ Wl,
             const float* __restrict__ bl, float* __restrict__ out)
{
    __shared__ float ws_a[NHID];
    __shared__ float ws_w[NHID * NCLASS];
    __shared__ float ws_b[NCLASS];
    __shared__ float ws_b2[NMETA * NHID];
    const int t = threadIdx.x;
    if (t < NHID) ws_a[t] = a[t];
    for (int idx = t; idx < NHID * NCLASS; idx += 256) ws_w[idx] = Wl[idx];
    if (t < NCLASS) ws_b[t] = bl[t];
    if (t < NMETA * NHID) ws_b2[t] = b2[t];
    __syncthreads();

    const int n = blockIdx.x * 256 + t;

    float hv[NMETA][NHID];
#pragma unroll
    for (int m = 0; m < NMETA; ++m) {
#pragma unroll
        for (int d4 = 0; d4 < NHID / 4; ++d4) {
            f32x4 s = {0.f,0.f,0.f,0.f};
#pragma unroll
            for (int kz = 0; kz < KSPLIT; ++kz) {
                const f32x4* hp = (const f32x4*)(h2p4 +
                    (((size_t)kz * NMETA + m) * NNODES + n) * NHID);
                s += hp[d4];
            }
#pragma unroll
            for (int e = 0; e < 4; ++e) {
                float val = s[e] + ws_b2[m * NHID + d4 * 4 + e];
                hv[m][d4 * 4 + e] = val > 0.f ? val : 0.f;
            }
        }
    }

    float em[NMETA];
#pragma unroll
    for (int m = 0; m < NMETA; ++m) {
        float d = 0.f;
#pragma unroll
        for (int h = 0; h < NHID; ++h) d += hv[m][h] * ws_a[h];
        em[m] = d > 0.f ? d : ALPHA * d;
    }

    float mx = fmaxf(em[0], fmaxf(em[1], em[2]));
    float w0 = __expf(em[0] - mx), w1 = __expf(em[1] - mx), w2 = __expf(em[2] - mx);
    float inv = 1.f / (w0 + w1 + w2);
    w0 *= inv; w1 *= inv; w2 *= inv;

    float o[NHID];
#pragma unroll
    for (int d = 0; d < NHID; ++d)
        o[d] = w0 * hv[0][d] + w1 * hv[1][d] + w2 * hv[2][d];

    float lg[NCLASS];
#pragma unroll
    for (int c = 0; c < NCLASS; ++c) lg[c] = ws_b[c];
    for (int d = 0; d < NHID; ++d) {
        const float od = o[d];
#pragma unroll
        for (int c = 0; c < NCLASS; ++c) lg[c] += od * ws_w[d * NCLASS + c];
    }
#pragma unroll
    for (int c = 0; c < NCLASS; ++c) lg[c] = lg[c] > 0.f ? lg[c] : 0.f;

    float lmx = lg[0];
#pragma unroll
    for (int c = 1; c < NCLASS; ++c) lmx = fmaxf(lmx, lg[c]);
    float ls = 0.f;
#pragma unroll
    for (int c = 0; c < NCLASS; ++c) ls += __expf(lg[c] - lmx);
    const float lse = lmx + __logf(ls);
#pragma unroll
    for (int c = 0; c < NCLASS; ++c)
        out[(size_t)n * NCLASS + c] = lg[c] - lse;
}

// ---------------------------------------------------------------------------
extern "C" void kernel_launch(void* const* d_in, const int* in_sizes, int n_in,
                              void* d_out, int out_size, void* d_ws, size_t ws_size,
                              hipStream_t stream) {
    const float* x    = (const float*)d_in[0];
    const float* adjs = (const float*)d_in[1];
    const float* W1   = (const float*)d_in[2];
    const float* b1   = (const float*)d_in[3];
    const float* W2   = (const float*)d_in[4];
    const float* b2   = (const float*)d_in[5];
    const float* a    = (const float*)d_in[6];
    const float* Wl   = (const float*)d_in[7];
    const float* bl   = (const float*)d_in[8];
    float* out = (float*)d_out;

    char* ws = (char*)d_ws;
    // layout: T1t 1.5MB @0 | T2t8 0.75MB @2MB | h1p4 12MB @3MB |
    //         h2p4 12MB @16MB | A8 201.3MB @32MB
    __bf16*        T1t  = (__bf16*)(ws);
    unsigned char* T2t8 = (unsigned char*)(ws + (2ull  << 20));
    float*         h1p4 = (float*)        (ws + (3ull  << 20));
    float*         h2p4 = (float*)        (ws + (16ull << 20));
    unsigned char* A8   = (unsigned char*)(ws + (32ull << 20));

    dim3 gsmall(NNODES / 256, NMETA);
    dim3 gspmm(NNODES / 32, KSPLIT, NMETA);

    k_xw   <<<gsmall, 256, 0, stream>>>(x, W1, T1t);
    k_spmm1<<<gspmm,   64, 0, stream>>>(adjs, T1t, A8, h1p4);
    k_hw   <<<gsmall, 256, 0, stream>>>(h1p4, b1, W2, T2t8);
    k_spmm2<<<gspmm,   64, 0, stream>>>(A8, T2t8, h2p4);
    k_final<<<NNODES / 256, 256, 0, stream>>>(h2p4, b2, a, Wl, bl, out);
}

// Round 3
// 323.859 us; speedup vs baseline: 1.1250x; 1.0823x over previous
//
#include <hip/hip_runtime.h>

#define NNODES 8192
#define NFEAT  128
#define NHID   32
#define NMETA  3
#define NCLASS 16
#define ALPHA  0.2f
#define KSPLIT 4
#define KRANGE (NNODES / KSPLIT)   // 2048 (pass-2 k-split)
#define BK     256                 // pass-1 k-tile (f32)
#define NT     (NNODES / BK)       // 32 tiles

typedef __attribute__((ext_vector_type(4))) float        f32x4;
typedef __attribute__((ext_vector_type(8))) __bf16       bf16x8;
typedef __attribute__((ext_vector_type(4))) __bf16       bf16x4;
typedef __attribute__((ext_vector_type(2))) unsigned int u32x2;

// A8 fragment layout (same as R2): A8[m][frag=u/16][kb=k/32][lane][8B]
#define A8_FRAGS_PER_M   (NNODES / 16)            // 512
#define A8_KBLKS         (NNODES / 32)            // 256
__device__ __forceinline__ size_t a8_off(int m, int frag, int kb, int lane) {
    return ((((size_t)m * A8_FRAGS_PER_M + frag) * A8_KBLKS + kb) * 64 + lane) * 8;
}

// ---------------------------------------------------------------------------
// Kernel 1: Btf = fragment-major bf16 of (x @ W1)^T.
// Layout: Btf[m][kb(256)][cgrp(2)][lane(64)][8 bf16]; lane = kg*16 + (c&15),
// j = k&7, kg = (k&31)>>3  — exactly the mfma_16x16x32 B-fragment order.
// ---------------------------------------------------------------------------
__global__ __launch_bounds__(256)
void k_xw(const float* __restrict__ x, const float* __restrict__ W1,
          __bf16* __restrict__ Btf)
{
    __shared__ float w[NFEAT * NHID];
    const int m = blockIdx.y, t = threadIdx.x;
    for (int idx = t; idx < NFEAT * NHID; idx += 256)
        w[idx] = W1[m * NFEAT * NHID + idx];
    __syncthreads();

    const int v = blockIdx.x * 256 + t;
    float acc[NHID];
#pragma unroll
    for (int h = 0; h < NHID; ++h) acc[h] = 0.f;
    const f32x4* xr = (const f32x4*)(x + (size_t)v * NFEAT);
    for (int f4 = 0; f4 < NFEAT / 4; ++f4) {
        f32x4 xv = xr[f4];
#pragma unroll
        for (int ff = 0; ff < 4; ++ff) {
            float xs = xv[ff];
#pragma unroll
            for (int h = 0; h < NHID; ++h)
                acc[h] += xs * w[(f4 * 4 + ff) * NHID + h];
        }
    }
    const int kb = v >> 5, q = v & 31, kg = q >> 3, j = q & 7;
    __bf16* base = Btf + ((size_t)m * A8_KBLKS + kb) * 1024;  // 2*64*8 per kb
#pragma unroll
    for (int c = 0; c < NHID; ++c) {
        const int cgrp = c >> 4;
        const int lane = kg * 16 + (c & 15);
        base[(cgrp * 64 + lane) * 8 + j] = (__bf16)acc[c];
    }
}

// ---------------------------------------------------------------------------
// Kernel 2: pass-1 spmm, LDS-staged contiguous reads.
// Block: 256 thr (4 waves), 32 output rows, full K. Wave w owns k-slice
// [w*64, w*64+64) of each 256-wide tile. Double-buffered LDS, 1 barrier/tile.
// Also side-writes fp8(adj*8192) MFMA fragments for pass 2 and produces
// FINAL h1 = relu(A@T1 + b1) via in-LDS cross-wave reduce.
// ---------------------------------------------------------------------------
__global__ __launch_bounds__(256, 3)
void k_spmm1(const float* __restrict__ adj, const __bf16* __restrict__ Btf,
             const float* __restrict__ b1, unsigned char* __restrict__ A8,
             __bf16* __restrict__ h1)
{
    __shared__ __align__(16) __bf16 lds[2 * 32 * BK];   // 2 x 16 KB
    const int tid  = threadIdx.x;
    const int lane = tid & 63;
    const int w    = tid >> 6;
    const int ln15 = lane & 15;
    const int kg   = lane >> 4;
    const int bx   = blockIdx.x;
    const int m    = blockIdx.y;
    const int u0   = bx * 32;

    const float*  Arow = adj + (size_t)m * NNODES * NNODES
                             + (size_t)(u0 + w * 8) * NNODES;
    const __bf16* Bb   = Btf + (size_t)m * A8_KBLKS * 1024;

    f32x4 acc00 = {0.f,0.f,0.f,0.f}, acc01 = {0.f,0.f,0.f,0.f};
    f32x4 acc10 = {0.f,0.f,0.f,0.f}, acc11 = {0.f,0.f,0.f,0.f};

    f32x4 st[8];
    // prologue: load tile 0 (each instr: 1KB contiguous from one row)
#pragma unroll
    for (int rr = 0; rr < 8; ++rr)
        st[rr] = *(const f32x4*)(Arow + (size_t)rr * NNODES + lane * 4);

    for (int t = 0; t < NT; ++t) {
        const int buf = (t & 1) * (32 * BK);
        // convert + write tile t into LDS (XOR swizzle on 8-bf16 granularity)
#pragma unroll
        for (int rr = 0; rr < 8; ++rr) {
            const int row = w * 8 + rr;
            bf16x4 c4;
#pragma unroll
            for (int e = 0; e < 4; ++e) c4[e] = (__bf16)st[rr][e];
            const int idx = buf + row * BK + lane * 4;
            *(bf16x4*)(&lds[idx ^ (rr << 3)]) = c4;
        }
        __syncthreads();   // tile t staged; prev-tile reads all complete

        // issue tile t+1 loads early (overlap the MFMA phase below)
        if (t + 1 < NT) {
            const float* An = Arow + (size_t)(t + 1) * BK;
#pragma unroll
            for (int rr = 0; rr < 8; ++rr)
                st[rr] = *(const f32x4*)(An + (size_t)rr * NNODES + lane * 4);
        }

        // MFMA phase on tile t, wave's k-slice
#pragma unroll
        for (int kk = 0; kk < 2; ++kk) {
            const int klocal = w * 64 + kk * 32;
            const int kb     = t * 8 + w * 2 + kk;
            const int i0 = (buf + ln15 * BK + klocal + kg * 8) ^ ((ln15 & 7) << 3);
            const int i1 = (buf + (ln15 + 16) * BK + klocal + kg * 8) ^ ((ln15 & 7) << 3);
            bf16x8 a0 = *(const bf16x8*)(&lds[i0]);
            bf16x8 a1 = *(const bf16x8*)(&lds[i1]);
            bf16x8 b0 = *(const bf16x8*)(Bb + ((size_t)kb * 2 + 0) * 512 + lane * 8);
            bf16x8 b1f= *(const bf16x8*)(Bb + ((size_t)kb * 2 + 1) * 512 + lane * 8);
            acc00 = __builtin_amdgcn_mfma_f32_16x16x32_bf16(a0, b0, acc00, 0, 0, 0);
            acc01 = __builtin_amdgcn_mfma_f32_16x16x32_bf16(a0, b1f, acc01, 0, 0, 0);
            acc10 = __builtin_amdgcn_mfma_f32_16x16x32_bf16(a1, b0, acc10, 0, 0, 0);
            acc11 = __builtin_amdgcn_mfma_f32_16x16x32_bf16(a1, b1f, acc11, 0, 0, 0);

            // fp8(adj*8192) fragment side-write (frag order = lane j order)
            const float S = 8192.0f;
            unsigned int p; u32x2 q;
            p = __builtin_amdgcn_cvt_pk_fp8_f32((float)a0[0]*S, (float)a0[1]*S, 0u, false);
            p = __builtin_amdgcn_cvt_pk_fp8_f32((float)a0[2]*S, (float)a0[3]*S, p,  true);
            q.x = p;
            p = __builtin_amdgcn_cvt_pk_fp8_f32((float)a0[4]*S, (float)a0[5]*S, 0u, false);
            p = __builtin_amdgcn_cvt_pk_fp8_f32((float)a0[6]*S, (float)a0[7]*S, p,  true);
            q.y = p;
            *(u32x2*)(A8 + a8_off(m, bx * 2 + 0, kb, lane)) = q;
            p = __builtin_amdgcn_cvt_pk_fp8_f32((float)a1[0]*S, (float)a1[1]*S, 0u, false);
            p = __builtin_amdgcn_cvt_pk_fp8_f32((float)a1[2]*S, (float)a1[3]*S, p,  true);
            q.x = p;
            p = __builtin_amdgcn_cvt_pk_fp8_f32((float)a1[4]*S, (float)a1[5]*S, 0u, false);
            p = __builtin_amdgcn_cvt_pk_fp8_f32((float)a1[6]*S, (float)a1[7]*S, p,  true);
            q.y = p;
            *(u32x2*)(A8 + a8_off(m, bx * 2 + 1, kb, lane)) = q;
        }
    }

    __syncthreads();
    // cross-wave k-reduce in LDS, then bias+relu -> final h1 (bf16)
    float* red = (float*)lds;            // 4 waves x 32 x 32 f32 = 16 KB
#pragma unroll
    for (int i = 0; i < 2; ++i)
#pragma unroll
        for (int j = 0; j < 2; ++j) {
            f32x4 acc = (i == 0) ? (j == 0 ? acc00 : acc01)
                                 : (j == 0 ? acc10 : acc11);
            const int c = 16 * j + ln15;
#pragma unroll
            for (int e = 0; e < 4; ++e) {
                const int u = 16 * i + 4 * kg + e;
                red[(w * 1024) + u * 32 + c] = acc[e];
            }
        }
    __syncthreads();

    {
        const int u  = tid >> 3;
        const int c0 = (tid & 7) * 4;
        f32x4 s = *(const f32x4*)(&red[u * 32 + c0]);
#pragma unroll
        for (int ww = 1; ww < 4; ++ww)
            s += *(const f32x4*)(&red[ww * 1024 + u * 32 + c0]);
        bf16x4 o4;
#pragma unroll
        for (int e = 0; e < 4; ++e) {
            float val = s[e] + b1[m * NHID + c0 + e];
            o4[e] = (__bf16)(val > 0.f ? val : 0.f);
        }
        *(bf16x4*)(h1 + ((size_t)m * NNODES + u0 + u) * NHID + c0) = o4;
    }
}

// ---------------------------------------------------------------------------
// Kernel 3: T2t8[m][d][v] = fp8(64 * (h1[m][v][:] @ W2[m]))   (natural k-order)
// ---------------------------------------------------------------------------
__global__ __launch_bounds__(256)
void k_hw(const __bf16* __restrict__ h1, const float* __restrict__ W2,
          unsigned char* __restrict__ T2t8)
{
    __shared__ float w[NHID * NHID];
    const int m = blockIdx.y, t = threadIdx.x;
    for (int idx = t; idx < NHID * NHID; idx += 256)
        w[idx] = W2[m * NHID * NHID + idx];
    __syncthreads();

    const int v = blockIdx.x * 256 + t;
    const __bf16* hr = h1 + ((size_t)m * NNODES + v) * NHID;
    float h[NHID];
#pragma unroll
    for (int i = 0; i < 4; ++i) {
        bf16x8 hb = *(const bf16x8*)(hr + i * 8);
#pragma unroll
        for (int e = 0; e < 8; ++e) h[i * 8 + e] = (float)hb[e];
    }

    float acc[NHID];
#pragma unroll
    for (int d = 0; d < NHID; ++d) acc[d] = 0.f;
    for (int hh = 0; hh < NHID; ++hh) {
        const float hs = h[hh];
#pragma unroll
        for (int d = 0; d < NHID; ++d) acc[d] += hs * w[hh * NHID + d];
    }
#pragma unroll
    for (int d = 0; d < NHID; ++d) {
        unsigned int p = __builtin_amdgcn_cvt_pk_fp8_f32(acc[d] * 64.0f, 0.f, 0u, false);
        T2t8[((size_t)m * NHID + d) * NNODES + v] = (unsigned char)(p & 0xff);
    }
}

// ---------------------------------------------------------------------------
// Kernel 4: pass-2 spmm (fp8 MFMA on A8 frags + T2t8) -> h2p4 partials
// (unchanged from R2 — control)
// ---------------------------------------------------------------------------
__global__ __launch_bounds__(64)
void k_spmm2(const unsigned char* __restrict__ A8,
             const unsigned char* __restrict__ T2t8,
             float* __restrict__ h2p4)
{
    const int lane = threadIdx.x;
    const int ln15 = lane & 15;
    const int kg   = lane >> 4;
    const int bx   = blockIdx.x;
    const int kz   = blockIdx.y;
    const int m    = blockIdx.z;
    const int u0   = bx * 32;
    const int kbeg = kz * KRANGE;

    const long* A8f0 = (const long*)(A8 + a8_off(m, bx * 2 + 0, 0, lane));
    const long* A8f1 = (const long*)(A8 + a8_off(m, bx * 2 + 1, 0, lane));
    const unsigned char* B0 = T2t8 + (size_t)m * NHID * NNODES
                                   + (size_t)ln15 * NNODES + kg * 8;
    const unsigned char* B1 = B0 + (size_t)16 * NNODES;

    f32x4 acc00 = {0.f,0.f,0.f,0.f}, acc01 = {0.f,0.f,0.f,0.f};
    f32x4 acc10 = {0.f,0.f,0.f,0.f}, acc11 = {0.f,0.f,0.f,0.f};

    for (int k0 = kbeg; k0 < kbeg + KRANGE; k0 += 256) {
#pragma unroll
        for (int kk = 0; kk < 8; ++kk) {
            const int k  = k0 + kk * 32;
            const int kb = k >> 5;
            long a0 = A8f0[(size_t)kb * 64];
            long a1 = A8f1[(size_t)kb * 64];
            long b0 = *(const long*)(B0 + k);
            long b1 = *(const long*)(B1 + k);
            acc00 = __builtin_amdgcn_mfma_f32_16x16x32_fp8_fp8(a0, b0, acc00, 0, 0, 0);
            acc01 = __builtin_amdgcn_mfma_f32_16x16x32_fp8_fp8(a0, b1, acc01, 0, 0, 0);
            acc10 = __builtin_amdgcn_mfma_f32_16x16x32_fp8_fp8(a1, b0, acc10, 0, 0, 0);
            acc11 = __builtin_amdgcn_mfma_f32_16x16x32_fp8_fp8(a1, b1, acc11, 0, 0, 0);
        }
    }

    const float INV = 1.0f / (8192.0f * 64.0f);
    float* hp = h2p4 + (((size_t)kz * NMETA + m) * NNODES) * NHID;
#pragma unroll
    for (int i = 0; i < 2; ++i)
#pragma unroll
        for (int j = 0; j < 2; ++j) {
            f32x4 acc = (i == 0) ? (j == 0 ? acc00 : acc01)
                                 : (j == 0 ? acc10 : acc11);
            const int c = 16 * j + ln15;
#pragma unroll
            for (int e = 0; e < 4; ++e) {
                const int u = u0 + 16 * i + 4 * kg + e;
                hp[(size_t)u * NHID + c] = acc[e] * INV;
            }
        }
}

// ---------------------------------------------------------------------------
// Kernel 5: h2 = relu(sum_kz h2p4 + b2); attention + linear + log_softmax
// (unchanged from R2)
// ---------------------------------------------------------------------------
__global__ __launch_bounds__(256)
void k_final(const float* __restrict__ h2p4, const float* __restrict__ b2,
             const float* __restrict__ a, const float* __restrict__ Wl,
             const float* __restrict__ bl, float* __restrict__ out)
{
    __shared__ float ws_a[NHID];
    __shared__ float ws_w[NHID * NCLASS];
    __shared__ float ws_b[NCLASS];
    __shared__ float ws_b2[NMETA * NHID];
    const int t = threadIdx.x;
    if (t < NHID) ws_a[t] = a[t];
    for (int idx = t; idx < NHID * NCLASS; idx += 256) ws_w[idx] = Wl[idx];
    if (t < NCLASS) ws_b[t] = bl[t];
    if (t < NMETA * NHID) ws_b2[t] = b2[t];
    __syncthreads();

    const int n = blockIdx.x * 256 + t;

    float hv[NMETA][NHID];
#pragma unroll
    for (int m = 0; m < NMETA; ++m) {
#pragma unroll
        for (int d4 = 0; d4 < NHID / 4; ++d4) {
            f32x4 s = {0.f,0.f,0.f,0.f};
#pragma unroll
            for (int kz = 0; kz < KSPLIT; ++kz) {
                const f32x4* hp = (const f32x4*)(h2p4 +
                    (((size_t)kz * NMETA + m) * NNODES + n) * NHID);
                s += hp[d4];
            }
#pragma unroll
            for (int e = 0; e < 4; ++e) {
                float val = s[e] + ws_b2[m * NHID + d4 * 4 + e];
                hv[m][d4 * 4 + e] = val > 0.f ? val : 0.f;
            }
        }
    }

    float em[NMETA];
#pragma unroll
    for (int m = 0; m < NMETA; ++m) {
        float d = 0.f;
#pragma unroll
        for (int h = 0; h < NHID; ++h) d += hv[m][h] * ws_a[h];
        em[m] = d > 0.f ? d : ALPHA * d;
    }

    float mx = fmaxf(em[0], fmaxf(em[1], em[2]));
    float w0 = __expf(em[0] - mx), w1 = __expf(em[1] - mx), w2 = __expf(em[2] - mx);
    float inv = 1.f / (w0 + w1 + w2);
    w0 *= inv; w1 *= inv; w2 *= inv;

    float o[NHID];
#pragma unroll
    for (int d = 0; d < NHID; ++d)
        o[d] = w0 * hv[0][d] + w1 * hv[1][d] + w2 * hv[2][d];

    float lg[NCLASS];
#pragma unroll
    for (int c = 0; c < NCLASS; ++c) lg[c] = ws_b[c];
    for (int d = 0; d < NHID; ++d) {
        const float od = o[d];
#pragma unroll
        for (int c = 0; c < NCLASS; ++c) lg[c] += od * ws_w[d * NCLASS + c];
    }
#pragma unroll
    for (int c = 0; c < NCLASS; ++c) lg[c] = lg[c] > 0.f ? lg[c] : 0.f;

    float lmx = lg[0];
#pragma unroll
    for (int c = 1; c < NCLASS; ++c) lmx = fmaxf(lmx, lg[c]);
    float ls = 0.f;
#pragma unroll
    for (int c = 0; c < NCLASS; ++c) ls += __expf(lg[c] - lmx);
    const float lse = lmx + __logf(ls);
#pragma unroll
    for (int c = 0; c < NCLASS; ++c)
        out[(size_t)n * NCLASS + c] = lg[c] - lse;
}

// ---------------------------------------------------------------------------
extern "C" void kernel_launch(void* const* d_in, const int* in_sizes, int n_in,
                              void* d_out, int out_size, void* d_ws, size_t ws_size,
                              hipStream_t stream) {
    const float* x    = (const float*)d_in[0];
    const float* adjs = (const float*)d_in[1];
    const float* W1   = (const float*)d_in[2];
    const float* b1   = (const float*)d_in[3];
    const float* W2   = (const float*)d_in[4];
    const float* b2   = (const float*)d_in[5];
    const float* a    = (const float*)d_in[6];
    const float* Wl   = (const float*)d_in[7];
    const float* bl   = (const float*)d_in[8];
    float* out = (float*)d_out;

    char* ws = (char*)d_ws;
    // layout: Btf 1.5MB @0 | T2t8 0.75MB @2MB | h1 1.5MB @3MB |
    //         h2p4 12.6MB @16MB | A8 201.3MB @32MB
    __bf16*        Btf  = (__bf16*)(ws);
    unsigned char* T2t8 = (unsigned char*)(ws + (2ull  << 20));
    __bf16*        h1   = (__bf16*)       (ws + (3ull  << 20));
    float*         h2p4 = (float*)        (ws + (16ull << 20));
    unsigned char* A8   = (unsigned char*)(ws + (32ull << 20));

    dim3 gsmall(NNODES / 256, NMETA);

    k_xw   <<<gsmall, 256, 0, stream>>>(x, W1, Btf);
    k_spmm1<<<dim3(NNODES / 32, NMETA), 256, 0, stream>>>(adjs, Btf, b1, A8, h1);
    k_hw   <<<gsmall, 256, 0, stream>>>(h1, W2, T2t8);
    k_spmm2<<<dim3(NNODES / 32, KSPLIT, NMETA), 64, 0, stream>>>(A8, T2t8, h2p4);
    k_final<<<NNODES / 256, 256, 0, stream>>>(h2p4, b2, a, Wl, bl, out);
}

// Round 4
// 284.896 us; speedup vs baseline: 1.2788x; 1.1368x over previous
//
#include <hip/hip_runtime.h>

#define NNODES 8192
#define NFEAT  128
#define NHID   32
#define NMETA  3
#define NCLASS 16
#define ALPHA  0.2f
#define KSPLIT 4
#define KRANGE (NNODES / KSPLIT)   // 2048 (pass-2 k-split)
#define BK     256                 // pass-1 k-tile (f32)
#define NT     (NNODES / BK)       // 32 tiles

typedef __attribute__((ext_vector_type(4))) float        f32x4;
typedef __attribute__((ext_vector_type(8))) __bf16       bf16x8;
typedef __attribute__((ext_vector_type(4))) __bf16       bf16x4;
typedef __attribute__((ext_vector_type(2))) unsigned int u32x2;

// A8 fragment layout: A8[m][frag=u/16][kb=k/32][lane][8B]
#define A8_FRAGS_PER_M   (NNODES / 16)            // 512
#define A8_KBLKS         (NNODES / 32)            // 256
__device__ __forceinline__ size_t a8_off(int m, int frag, int kb, int lane) {
    return ((((size_t)m * A8_FRAGS_PER_M + frag) * A8_KBLKS + kb) * 64 + lane) * 8;
}

// ---------------------------------------------------------------------------
// Kernel 1: Btf = fragment-major bf16 of (x @ W1)^T.
// ---------------------------------------------------------------------------
__global__ __launch_bounds__(256)
void k_xw(const float* __restrict__ x, const float* __restrict__ W1,
          __bf16* __restrict__ Btf)
{
    __shared__ float w[NFEAT * NHID];
    const int m = blockIdx.y, t = threadIdx.x;
    for (int idx = t; idx < NFEAT * NHID; idx += 256)
        w[idx] = W1[m * NFEAT * NHID + idx];
    __syncthreads();

    const int v = blockIdx.x * 256 + t;
    float acc[NHID];
#pragma unroll
    for (int h = 0; h < NHID; ++h) acc[h] = 0.f;
    const f32x4* xr = (const f32x4*)(x + (size_t)v * NFEAT);
    for (int f4 = 0; f4 < NFEAT / 4; ++f4) {
        f32x4 xv = xr[f4];
#pragma unroll
        for (int ff = 0; ff < 4; ++ff) {
            float xs = xv[ff];
#pragma unroll
            for (int h = 0; h < NHID; ++h)
                acc[h] += xs * w[(f4 * 4 + ff) * NHID + h];
        }
    }
    const int kb = v >> 5, q = v & 31, kg = q >> 3, j = q & 7;
    __bf16* base = Btf + ((size_t)m * A8_KBLKS + kb) * 1024;
#pragma unroll
    for (int c = 0; c < NHID; ++c) {
        const int cgrp = c >> 4;
        const int lane = kg * 16 + (c & 15);
        base[(cgrp * 64 + lane) * 8 + j] = (__bf16)acc[c];
    }
}

// ---------------------------------------------------------------------------
// Kernel 2: pass-1 spmm, LDS-staged contiguous reads. NT loads on adj so the
// streaming 805MB doesn't thrash L2/L3 (protects A8 residency for pass 2).
// ---------------------------------------------------------------------------
__global__ __launch_bounds__(256, 3)
void k_spmm1(const float* __restrict__ adj, const __bf16* __restrict__ Btf,
             const float* __restrict__ b1, unsigned char* __restrict__ A8,
             __bf16* __restrict__ h1)
{
    __shared__ __align__(16) __bf16 lds[2 * 32 * BK];   // 2 x 16 KB
    const int tid  = threadIdx.x;
    const int lane = tid & 63;
    const int w    = tid >> 6;
    const int ln15 = lane & 15;
    const int kg   = lane >> 4;
    const int bx   = blockIdx.x;
    const int m    = blockIdx.y;
    const int u0   = bx * 32;

    const float*  Arow = adj + (size_t)m * NNODES * NNODES
                             + (size_t)(u0 + w * 8) * NNODES;
    const __bf16* Bb   = Btf + (size_t)m * A8_KBLKS * 1024;

    f32x4 acc00 = {0.f,0.f,0.f,0.f}, acc01 = {0.f,0.f,0.f,0.f};
    f32x4 acc10 = {0.f,0.f,0.f,0.f}, acc11 = {0.f,0.f,0.f,0.f};

    f32x4 st[8];
#pragma unroll
    for (int rr = 0; rr < 8; ++rr)
        st[rr] = __builtin_nontemporal_load(
            (const f32x4*)(Arow + (size_t)rr * NNODES + lane * 4));

    for (int t = 0; t < NT; ++t) {
        const int buf = (t & 1) * (32 * BK);
#pragma unroll
        for (int rr = 0; rr < 8; ++rr) {
            const int row = w * 8 + rr;
            bf16x4 c4;
#pragma unroll
            for (int e = 0; e < 4; ++e) c4[e] = (__bf16)st[rr][e];
            const int idx = buf + row * BK + lane * 4;
            *(bf16x4*)(&lds[idx ^ (rr << 3)]) = c4;
        }
        __syncthreads();

        if (t + 1 < NT) {
            const float* An = Arow + (size_t)(t + 1) * BK;
#pragma unroll
            for (int rr = 0; rr < 8; ++rr)
                st[rr] = __builtin_nontemporal_load(
                    (const f32x4*)(An + (size_t)rr * NNODES + lane * 4));
        }

#pragma unroll
        for (int kk = 0; kk < 2; ++kk) {
            const int klocal = w * 64 + kk * 32;
            const int kb     = t * 8 + w * 2 + kk;
            const int i0 = (buf + ln15 * BK + klocal + kg * 8) ^ ((ln15 & 7) << 3);
            const int i1 = (buf + (ln15 + 16) * BK + klocal + kg * 8) ^ ((ln15 & 7) << 3);
            bf16x8 a0 = *(const bf16x8*)(&lds[i0]);
            bf16x8 a1 = *(const bf16x8*)(&lds[i1]);
            bf16x8 b0 = *(const bf16x8*)(Bb + ((size_t)kb * 2 + 0) * 512 + lane * 8);
            bf16x8 b1f= *(const bf16x8*)(Bb + ((size_t)kb * 2 + 1) * 512 + lane * 8);
            acc00 = __builtin_amdgcn_mfma_f32_16x16x32_bf16(a0, b0, acc00, 0, 0, 0);
            acc01 = __builtin_amdgcn_mfma_f32_16x16x32_bf16(a0, b1f, acc01, 0, 0, 0);
            acc10 = __builtin_amdgcn_mfma_f32_16x16x32_bf16(a1, b0, acc10, 0, 0, 0);
            acc11 = __builtin_amdgcn_mfma_f32_16x16x32_bf16(a1, b1f, acc11, 0, 0, 0);

            const float S = 8192.0f;
            unsigned int p; u32x2 q;
            p = __builtin_amdgcn_cvt_pk_fp8_f32((float)a0[0]*S, (float)a0[1]*S, 0u, false);
            p = __builtin_amdgcn_cvt_pk_fp8_f32((float)a0[2]*S, (float)a0[3]*S, p,  true);
            q.x = p;
            p = __builtin_amdgcn_cvt_pk_fp8_f32((float)a0[4]*S, (float)a0[5]*S, 0u, false);
            p = __builtin_amdgcn_cvt_pk_fp8_f32((float)a0[6]*S, (float)a0[7]*S, p,  true);
            q.y = p;
            *(u32x2*)(A8 + a8_off(m, bx * 2 + 0, kb, lane)) = q;
            p = __builtin_amdgcn_cvt_pk_fp8_f32((float)a1[0]*S, (float)a1[1]*S, 0u, false);
            p = __builtin_amdgcn_cvt_pk_fp8_f32((float)a1[2]*S, (float)a1[3]*S, p,  true);
            q.x = p;
            p = __builtin_amdgcn_cvt_pk_fp8_f32((float)a1[4]*S, (float)a1[5]*S, 0u, false);
            p = __builtin_amdgcn_cvt_pk_fp8_f32((float)a1[6]*S, (float)a1[7]*S, p,  true);
            q.y = p;
            *(u32x2*)(A8 + a8_off(m, bx * 2 + 1, kb, lane)) = q;
        }
    }

    __syncthreads();
    float* red = (float*)lds;
#pragma unroll
    for (int i = 0; i < 2; ++i)
#pragma unroll
        for (int j = 0; j < 2; ++j) {
            f32x4 acc = (i == 0) ? (j == 0 ? acc00 : acc01)
                                 : (j == 0 ? acc10 : acc11);
            const int c = 16 * j + ln15;
#pragma unroll
            for (int e = 0; e < 4; ++e) {
                const int u = 16 * i + 4 * kg + e;
                red[(w * 1024) + u * 32 + c] = acc[e];
            }
        }
    __syncthreads();

    {
        const int u  = tid >> 3;
        const int c0 = (tid & 7) * 4;
        f32x4 s = *(const f32x4*)(&red[u * 32 + c0]);
#pragma unroll
        for (int ww = 1; ww < 4; ++ww)
            s += *(const f32x4*)(&red[ww * 1024 + u * 32 + c0]);
        bf16x4 o4;
#pragma unroll
        for (int e = 0; e < 4; ++e) {
            float val = s[e] + b1[m * NHID + c0 + e];
            o4[e] = (__bf16)(val > 0.f ? val : 0.f);
        }
        *(bf16x4*)(h1 + ((size_t)m * NNODES + u0 + u) * NHID + c0) = o4;
    }
}

// ---------------------------------------------------------------------------
// Kernel 3: T2t8[m][d][v] = fp8(64 * (h1[m][v][:] @ W2[m]))
// ---------------------------------------------------------------------------
__global__ __launch_bounds__(256)
void k_hw(const __bf16* __restrict__ h1, const float* __restrict__ W2,
          unsigned char* __restrict__ T2t8)
{
    __shared__ float w[NHID * NHID];
    const int m = blockIdx.y, t = threadIdx.x;
    for (int idx = t; idx < NHID * NHID; idx += 256)
        w[idx] = W2[m * NHID * NHID + idx];
    __syncthreads();

    const int v = blockIdx.x * 256 + t;
    const __bf16* hr = h1 + ((size_t)m * NNODES + v) * NHID;
    float h[NHID];
#pragma unroll
    for (int i = 0; i < 4; ++i) {
        bf16x8 hb = *(const bf16x8*)(hr + i * 8);
#pragma unroll
        for (int e = 0; e < 8; ++e) h[i * 8 + e] = (float)hb[e];
    }

    float acc[NHID];
#pragma unroll
    for (int d = 0; d < NHID; ++d) acc[d] = 0.f;
    for (int hh = 0; hh < NHID; ++hh) {
        const float hs = h[hh];
#pragma unroll
        for (int d = 0; d < NHID; ++d) acc[d] += hs * w[hh * NHID + d];
    }
#pragma unroll
    for (int d = 0; d < NHID; ++d) {
        unsigned int p = __builtin_amdgcn_cvt_pk_fp8_f32(acc[d] * 64.0f, 0.f, 0u, false);
        T2t8[((size_t)m * NHID + d) * NNODES + v] = (unsigned char)(p & 0xff);
    }
}

// ---------------------------------------------------------------------------
// Kernel 4: pass-2 spmm (fp8 MFMA on A8 frags + T2t8) -> h2p4 partials
// ---------------------------------------------------------------------------
__global__ __launch_bounds__(64)
void k_spmm2(const unsigned char* __restrict__ A8,
             const unsigned char* __restrict__ T2t8,
             float* __restrict__ h2p4)
{
    const int lane = threadIdx.x;
    const int ln15 = lane & 15;
    const int kg   = lane >> 4;
    const int bx   = blockIdx.x;
    const int kz   = blockIdx.y;
    const int m    = blockIdx.z;
    const int u0   = bx * 32;
    const int kbeg = kz * KRANGE;

    const long* A8f0 = (const long*)(A8 + a8_off(m, bx * 2 + 0, 0, lane));
    const long* A8f1 = (const long*)(A8 + a8_off(m, bx * 2 + 1, 0, lane));
    const unsigned char* B0 = T2t8 + (size_t)m * NHID * NNODES
                                   + (size_t)ln15 * NNODES + kg * 8;
    const unsigned char* B1 = B0 + (size_t)16 * NNODES;

    f32x4 acc00 = {0.f,0.f,0.f,0.f}, acc01 = {0.f,0.f,0.f,0.f};
    f32x4 acc10 = {0.f,0.f,0.f,0.f}, acc11 = {0.f,0.f,0.f,0.f};

    for (int k0 = kbeg; k0 < kbeg + KRANGE; k0 += 256) {
#pragma unroll
        for (int kk = 0; kk < 8; ++kk) {
            const int k  = k0 + kk * 32;
            const int kb = k >> 5;
            long a0 = A8f0[(size_t)kb * 64];
            long a1 = A8f1[(size_t)kb * 64];
            long b0 = *(const long*)(B0 + k);
            long b1 = *(const long*)(B1 + k);
            acc00 = __builtin_amdgcn_mfma_f32_16x16x32_fp8_fp8(a0, b0, acc00, 0, 0, 0);
            acc01 = __builtin_amdgcn_mfma_f32_16x16x32_fp8_fp8(a0, b1, acc01, 0, 0, 0);
            acc10 = __builtin_amdgcn_mfma_f32_16x16x32_fp8_fp8(a1, b0, acc10, 0, 0, 0);
            acc11 = __builtin_amdgcn_mfma_f32_16x16x32_fp8_fp8(a1, b1, acc11, 0, 0, 0);
        }
    }

    const float INV = 1.0f / (8192.0f * 64.0f);
    float* hp = h2p4 + (((size_t)kz * NMETA + m) * NNODES) * NHID;
#pragma unroll
    for (int i = 0; i < 2; ++i)
#pragma unroll
        for (int j = 0; j < 2; ++j) {
            f32x4 acc = (i == 0) ? (j == 0 ? acc00 : acc01)
                                 : (j == 0 ? acc10 : acc11);
            const int c = 16 * j + ln15;
#pragma unroll
            for (int e = 0; e < 4; ++e) {
                const int u = u0 + 16 * i + 4 * kg + e;
                hp[(size_t)u * NHID + c] = acc[e] * INV;
            }
        }
}

// ---------------------------------------------------------------------------
// Kernel 5a: wide reduce  h2[m][n][:] = relu(sum_kz h2p4 + b2)
// thread = one (m, n, d4);  768 blocks x 256 thr
// ---------------------------------------------------------------------------
__global__ __launch_bounds__(256)
void k_red(const float* __restrict__ h2p4, const float* __restrict__ b2,
           float* __restrict__ h2)
{
    const int tid = blockIdx.x * 256 + threadIdx.x;   // 0 .. 196607
    const int d4  = tid & 7;
    const int nm  = tid >> 3;
    const int n   = nm & (NNODES - 1);
    const int m   = nm >> 13;

    f32x4 s = {0.f,0.f,0.f,0.f};
#pragma unroll
    for (int kz = 0; kz < KSPLIT; ++kz)
        s += *(const f32x4*)(h2p4 +
            (((size_t)kz * NMETA + m) * NNODES + n) * NHID + d4 * 4);

    f32x4 o;
#pragma unroll
    for (int e = 0; e < 4; ++e) {
        float val = s[e] + b2[m * NHID + d4 * 4 + e];
        o[e] = val > 0.f ? val : 0.f;
    }
    *(f32x4*)(h2 + ((size_t)m * NNODES + n) * NHID + d4 * 4) = o;
}

// ---------------------------------------------------------------------------
// Kernel 5b: attention + linear + log_softmax  (128 blocks x 64 thr)
// ---------------------------------------------------------------------------
__global__ __launch_bounds__(64)
void k_final(const float* __restrict__ h2, const float* __restrict__ a,
             const float* __restrict__ Wl, const float* __restrict__ bl,
             float* __restrict__ out)
{
    __shared__ float ws_a[NHID];
    __shared__ float ws_w[NHID * NCLASS];
    __shared__ float ws_b[NCLASS];
    const int t = threadIdx.x;
    if (t < NHID) ws_a[t] = a[t];
    for (int idx = t; idx < NHID * NCLASS; idx += 64) ws_w[idx] = Wl[idx];
    if (t < NCLASS) ws_b[t] = bl[t];
    __syncthreads();

    const int n = blockIdx.x * 64 + t;

    float hv[NMETA][NHID];
#pragma unroll
    for (int m = 0; m < NMETA; ++m) {
        const f32x4* hp = (const f32x4*)(h2 + ((size_t)m * NNODES + n) * NHID);
#pragma unroll
        for (int d4 = 0; d4 < NHID / 4; ++d4) {
            f32x4 v = hp[d4];
#pragma unroll
            for (int e = 0; e < 4; ++e) hv[m][d4 * 4 + e] = v[e];
        }
    }

    float em[NMETA];
#pragma unroll
    for (int m = 0; m < NMETA; ++m) {
        float d = 0.f;
#pragma unroll
        for (int h = 0; h < NHID; ++h) d += hv[m][h] * ws_a[h];
        em[m] = d > 0.f ? d : ALPHA * d;
    }

    float mx = fmaxf(em[0], fmaxf(em[1], em[2]));
    float w0 = __expf(em[0] - mx), w1 = __expf(em[1] - mx), w2 = __expf(em[2] - mx);
    float inv = 1.f / (w0 + w1 + w2);
    w0 *= inv; w1 *= inv; w2 *= inv;

    float o[NHID];
#pragma unroll
    for (int d = 0; d < NHID; ++d)
        o[d] = w0 * hv[0][d] + w1 * hv[1][d] + w2 * hv[2][d];

    float lg[NCLASS];
#pragma unroll
    for (int c = 0; c < NCLASS; ++c) lg[c] = ws_b[c];
    for (int d = 0; d < NHID; ++d) {
        const float od = o[d];
#pragma unroll
        for (int c = 0; c < NCLASS; ++c) lg[c] += od * ws_w[d * NCLASS + c];
    }
#pragma unroll
    for (int c = 0; c < NCLASS; ++c) lg[c] = lg[c] > 0.f ? lg[c] : 0.f;

    float lmx = lg[0];
#pragma unroll
    for (int c = 1; c < NCLASS; ++c) lmx = fmaxf(lmx, lg[c]);
    float ls = 0.f;
#pragma unroll
    for (int c = 0; c < NCLASS; ++c) ls += __expf(lg[c] - lmx);
    const float lse = lmx + __logf(ls);
#pragma unroll
    for (int c = 0; c < NCLASS; ++c)
        out[(size_t)n * NCLASS + c] = lg[c] - lse;
}

// ---------------------------------------------------------------------------
extern "C" void kernel_launch(void* const* d_in, const int* in_sizes, int n_in,
                              void* d_out, int out_size, void* d_ws, size_t ws_size,
                              hipStream_t stream) {
    const float* x    = (const float*)d_in[0];
    const float* adjs = (const float*)d_in[1];
    const float* W1   = (const float*)d_in[2];
    const float* b1   = (const float*)d_in[3];
    const float* W2   = (const float*)d_in[4];
    const float* b2   = (const float*)d_in[5];
    const float* a    = (const float*)d_in[6];
    const float* Wl   = (const float*)d_in[7];
    const float* bl   = (const float*)d_in[8];
    float* out = (float*)d_out;

    char* ws = (char*)d_ws;
    // layout: Btf 1.5MB @0 | T2t8 0.75MB @2MB | h1 1.5MB @3MB |
    //         h2 3MB @8MB | h2p4 12.6MB @16MB | A8 201.3MB @32MB
    __bf16*        Btf  = (__bf16*)(ws);
    unsigned char* T2t8 = (unsigned char*)(ws + (2ull  << 20));
    __bf16*        h1   = (__bf16*)       (ws + (3ull  << 20));
    float*         h2   = (float*)        (ws + (8ull  << 20));
    float*         h2p4 = (float*)        (ws + (16ull << 20));
    unsigned char* A8   = (unsigned char*)(ws + (32ull << 20));

    dim3 gsmall(NNODES / 256, NMETA);

    k_xw   <<<gsmall, 256, 0, stream>>>(x, W1, Btf);
    k_spmm1<<<dim3(NNODES / 32, NMETA), 256, 0, stream>>>(adjs, Btf, b1, A8, h1);
    k_hw   <<<gsmall, 256, 0, stream>>>(h1, W2, T2t8);
    k_spmm2<<<dim3(NNODES / 32, KSPLIT, NMETA), 64, 0, stream>>>(A8, T2t8, h2p4);
    k_red  <<<NMETA * NNODES * 8 / 256, 256, 0, stream>>>(h2p4, b2, h2);
    k_final<<<NNODES / 64, 64, 0, stream>>>(h2, a, Wl, bl, out);
}